// Round 1
// baseline (611.630 us; speedup 1.0000x reference)
//
#include <hip/hip_runtime.h>

// Problem constants
#define NW    8192
#define MAXW  20
#define BB    64
#define SS    256
#define CHS   128
#define CHE   64
#define HH    256
#define G3    768
#define WEM   300
#define CAPEM 16

typedef _Float16 half8  __attribute__((ext_vector_type(8)));
typedef _Float16 half4v __attribute__((ext_vector_type(4)));
typedef float    f32x4  __attribute__((ext_vector_type(4)));

// workspace layout (bytes)
#define WF_OFF  0                        // f16 w_hh frag-ordered, 2 dirs: 786432 B
#define GI_OFF  (2*G3*HH*2)              // f16 gi table, 2 dirs: 393216 B
#define EMS_OFF (GI_OFF + 2*CHS*G3*2)    // f32 ems, 2 dirs: 16777216 B

__device__ __forceinline__ float fast_sigmoid(float x) {
    float e = __builtin_amdgcn_exp2f(-1.442695041f * x);
    return __builtin_amdgcn_rcpf(1.0f + e);
}
__device__ __forceinline__ float fast_tanh(float x) {
    float e = __builtin_amdgcn_exp2f(2.885390082f * x);
    return 1.0f - 2.0f * __builtin_amdgcn_rcpf(1.0f + e);
}

// Fragment-ordered f16 weights: rows m = g*256 + wvv*16 + l16, k = kk*32 + q*8 + j.
// Wave's A-frag load in gru = one contiguous 1 KB segment.
__global__ void prep_w(const float* __restrict__ fw_whh, const float* __restrict__ bw_whh,
                       _Float16* __restrict__ Wf) {
    int dir = blockIdx.x / 48;
    int tile = blockIdx.x % 48;
    int g = tile >> 4, wvv = tile & 15;
    int t = threadIdx.x;                 // 512 = kk(8) * l16(16) * q(4)
    int kk = t >> 6;
    int l16 = (t >> 2) & 15;
    int q = t & 3;
    int m = g * 256 + wvv * 16 + l16;
    const float* src = (dir ? bw_whh : fw_whh) + m * HH + kk * 32 + q * 8;
    _Float16* d = Wf + (size_t)dir * G3 * HH + (((size_t)tile * 8 + kk) * 64 + l16 * 4 + q) * 8;
    #pragma unroll
    for (int j = 0; j < 8; ++j) d[j] = (_Float16)src[j];
}

// gi table (f16): gi[dir][c][j] = sum_e w_ih[j][e]*ch_em[c][e] + b_ih[j] + (j<512 ? b_hh[j] : 0)
__global__ void prep_gi(const float* __restrict__ ch_em,
                        const float* __restrict__ fw_wih, const float* __restrict__ fw_bih,
                        const float* __restrict__ fw_bhh,
                        const float* __restrict__ bw_wih, const float* __restrict__ bw_bih,
                        const float* __restrict__ bw_bhh,
                        _Float16* __restrict__ gi) {
    int bx = blockIdx.x;
    int dir = bx >> 7;
    int c = bx & 127;
    const float* wih = dir ? bw_wih : fw_wih;
    const float* bih = dir ? bw_bih : fw_bih;
    const float* bhh = dir ? bw_bhh : fw_bhh;
    const float* ce = ch_em + c * CHE;
    for (int jj = 0; jj < 3; ++jj) {
        int j = jj * 256 + threadIdx.x;
        float s = bih[j] + (j < 512 ? bhh[j] : 0.0f);
        const float* wr = wih + j * CHE;
        #pragma unroll
        for (int e = 0; e < CHE; ++e) s += wr[e] * ce[e];
        gi[(size_t)dir * CHS * G3 + c * G3 + j] = (_Float16)s;
    }
}

// GRU: 256 blocks (dir*128 + word-block) x 1024 thr (16 waves).
//
// Round-4 change: REMOVED the gilds LDS staging entirely. Evidence (round-3/4
// counters): FETCH 949 MB + WRITE 438 MB at VGPR_Count=64 == scratch-spill
// traffic (real traffic is ~30 MB); the staging loop's ~24 in-flight half8
// regs on top of the 48-reg accumulator was the register-pressure peak that
// forced the spill. Each gi element is consumed exactly once, so the gate
// phase now reads gi directly from L2 (table is 393 KB, fully L2-resident;
// 12x8B loads/thread/step, latency hidden across 4 waves/SIMD). This also
// drops LDS 138->39 KB and kills the stride-776 gilds bank conflicts.
// Peak live set in MFMA loop: 48 acc (AGPR-able) + 12 af + 4 bf + 16 hprev
// + addrs ~= 90 < 128 cap from __launch_bounds__(1024,4) -> no spill.
__global__ __launch_bounds__(1024, 4)
void gru(const int* __restrict__ ch, const int* __restrict__ rev_ch,
         const int* __restrict__ wlen,
         const float* __restrict__ fw_bhh, const float* __restrict__ bw_bhh,
         const _Float16* __restrict__ Wf, const _Float16* __restrict__ gi,
         float* __restrict__ ems) {
    int dir = blockIdx.x >> 7;
    int wblk = blockIdx.x & 127;
    int w0 = wblk * 64;
    const int* chp = dir ? rev_ch : ch;
    const _Float16* W = Wf + (size_t)dir * G3 * HH;
    const _Float16* gt = gi + (size_t)dir * CHS * G3;
    const float* bh = dir ? bw_bhh : fw_bhh;
    float* emsd = ems + (size_t)dir * NW * HH;

    int tid = threadIdx.x;
    int wv = tid >> 6;          // 0..15 -> h cols [wv*16, wv*16+16)
    int lane = tid & 63;
    int q = lane >> 4;          // 0..3
    int l16 = lane & 15;

    __shared__ __align__(16) _Float16 hbuf[64][264];     // h (f16), +8 pad (row stride 528 B == 4 dwords mod 32 banks)
    __shared__ int clds[64][MAXW];                       // chars, staged once
    __shared__ int wls[64];                              // lengths

    // one-time staging
    for (int i = tid; i < 64 * 264; i += 1024) (&hbuf[0][0])[i] = (_Float16)0.0f;
    if (tid < 64) wls[tid] = wlen[w0 + tid];
    for (int i = tid; i < 64 * MAXW; i += 1024) {
        int w = i / MAXW, t = i - w * MAXW;
        clds[w][t] = chp[(w0 + w) * MAXW + t];
    }
    f32x4 bhhn = *(const f32x4*)(bh + 512 + wv * 16 + q * 4);
    const f32x4 fz = {0.0f, 0.0f, 0.0f, 0.0f};
    f32x4 hprev[4] = {fz, fz, fz, fz};
    __syncthreads();

    #pragma unroll 1
    for (int t = 0; t < MAXW; ++t) {
        // MFMA: acc = W_hh x h^T, K = 256 in 8 k-tiles of 32
        f32x4 acc[3][4];
        #pragma unroll
        for (int g = 0; g < 3; ++g)
            #pragma unroll
            for (int ct = 0; ct < 4; ++ct) acc[g][ct] = fz;

        #pragma unroll
        for (int kk = 0; kk < 8; ++kk) {
            half8 af0 = *(const half8*)(W + (((size_t)(0 * 16 + wv) * 8 + kk) * 64 + l16 * 4 + q) * 8);
            half8 af1 = *(const half8*)(W + (((size_t)(1 * 16 + wv) * 8 + kk) * 64 + l16 * 4 + q) * 8);
            half8 af2 = *(const half8*)(W + (((size_t)(2 * 16 + wv) * 8 + kk) * 64 + l16 * 4 + q) * 8);
            #pragma unroll
            for (int ct = 0; ct < 4; ++ct) {
                half8 bf = *(const half8*)(&hbuf[ct * 16 + l16][kk * 32 + q * 8]);
                acc[0][ct] = __builtin_amdgcn_mfma_f32_16x16x32_f16(af0, bf, acc[0][ct], 0, 0, 0);
                acc[1][ct] = __builtin_amdgcn_mfma_f32_16x16x32_f16(af1, bf, acc[1][ct], 0, 0, 0);
                acc[2][ct] = __builtin_amdgcn_mfma_f32_16x16x32_f16(af2, bf, acc[2][ct], 0, 0, 0);
            }
        }

        __syncthreads();   // (c) all hbuf(t-1) reads done

        // (d) elementwise gates + h update; gi read DIRECTLY from L2 (one use
        // per element -> LDS staging was pure overhead + the spill trigger)
        #pragma unroll
        for (int ct = 0; ct < 4; ++ct) {
            int word = ct * 16 + l16;
            int c = clds[word][t];
            const _Float16* gr = gt + (size_t)c * G3 + wv * 16 + q * 4;
            half4v g0 = *(const half4v*)(gr);
            half4v g1 = *(const half4v*)(gr + 256);
            half4v g2 = *(const half4v*)(gr + 512);
            f32x4 hv = hprev[ct];
            f32x4 out4;
            half4v hh4;
            #pragma unroll
            for (int e = 0; e < 4; ++e) {
                float r  = fast_sigmoid(acc[0][ct][e] + (float)g0[e]);
                float z  = fast_sigmoid(acc[1][ct][e] + (float)g1[e]);
                float n  = fast_tanh((float)g2[e] + r * (acc[2][ct][e] + bhhn[e]));
                float hnew = n + z * (hv[e] - n);
                out4[e] = hnew;
                hh4[e] = (_Float16)hnew;
            }
            hprev[ct] = out4;
            *(half4v*)(&hbuf[word][wv * 16 + q * 4]) = hh4;
        }
        __syncthreads();   // (e) h(t) complete in hbuf

        // (f) coalesced ems writeback for words finishing at this step
        {
            int w = tid >> 4, t16 = tid & 15;
            if (wls[w] == t + 1) {
                const _Float16* src = &hbuf[w][t16 * 16];
                half8 a = *(const half8*)(src);
                half8 b = *(const half8*)(src + 8);
                f32x4 o0, o1, o2, o3;
                #pragma unroll
                for (int e = 0; e < 4; ++e) {
                    o0[e] = (float)a[e];     o1[e] = (float)a[4 + e];
                    o2[e] = (float)b[e];     o3[e] = (float)b[4 + e];
                }
                f32x4* dst = (f32x4*)(emsd + (size_t)(w0 + w) * HH + t16 * 16);
                dst[0] = o0; dst[1] = o1; dst[2] = o2; dst[3] = o3;
            }
        }
        // no barrier needed: (f) reads complete before any thread passes next (c)
    }
}

// Gather/concat: one block per (b,s) position; 207 f32x4 chunks of 828 f32.
// chunk map: [0,64) pre*m | [64,139) wem | [139,203) suf*m | [203,207) cap
__global__ void emit(const int* __restrict__ w, const int* __restrict__ wcap,
                     const int* __restrict__ wchs, const float* __restrict__ wmask,
                     const float* __restrict__ w_em, const float* __restrict__ cap_em,
                     const float* __restrict__ ems, float* __restrict__ out) {
    int pos = blockIdx.x;
    int c = threadIdx.x;
    if (c >= 207) return;
    int wi = w[pos], cap = wcap[pos], wch = wchs[pos];
    float m = wmask[pos];
    const f32x4* suf = (const f32x4*)(ems + (size_t)wch * HH);                   // fw = suffix
    const f32x4* pre = (const f32x4*)(ems + (size_t)NW * HH + (size_t)wch * HH); // bw = prefix
    const f32x4* wem = (const f32x4*)(w_em + (size_t)wi * WEM);
    const f32x4* cp4 = (const f32x4*)(cap_em + cap * CAPEM);
    f32x4 v;
    if (c < 64)       v = pre[c] * m;
    else if (c < 139) v = wem[c - 64];
    else if (c < 203) v = suf[c - 139] * m;
    else              v = cp4[c - 203];
    ((f32x4*)out)[(size_t)pos * 207 + c] = v;
}

extern "C" void kernel_launch(void* const* d_in, const int* in_sizes, int n_in,
                              void* d_out, int out_size, void* d_ws, size_t ws_size,
                              hipStream_t stream) {
    const int*   ch      = (const int*)d_in[0];
    const int*   rev_ch  = (const int*)d_in[1];
    const int*   w_len   = (const int*)d_in[2];
    const int*   w       = (const int*)d_in[3];
    const int*   w_cap   = (const int*)d_in[4];
    const int*   w_chs   = (const int*)d_in[5];
    const float* w_mask  = (const float*)d_in[6];
    const float* ch_em   = (const float*)d_in[7];
    const float* w_em    = (const float*)d_in[8];
    const float* cap_em  = (const float*)d_in[9];
    const float* fw_wih  = (const float*)d_in[10];
    const float* fw_whh  = (const float*)d_in[11];
    const float* fw_bih  = (const float*)d_in[12];
    const float* fw_bhh  = (const float*)d_in[13];
    const float* bw_wih  = (const float*)d_in[14];
    const float* bw_whh  = (const float*)d_in[15];
    const float* bw_bih  = (const float*)d_in[16];
    const float* bw_bhh  = (const float*)d_in[17];

    char* ws = (char*)d_ws;
    _Float16* Wf = (_Float16*)(ws + WF_OFF);
    _Float16* gi = (_Float16*)(ws + GI_OFF);
    float* ems   = (float*)(ws + EMS_OFF);
    float* out   = (float*)d_out;

    prep_w <<<96, 512, 0, stream>>>(fw_whh, bw_whh, Wf);
    prep_gi<<<256, 256, 0, stream>>>(ch_em, fw_wih, fw_bih, fw_bhh,
                                     bw_wih, bw_bih, bw_bhh, gi);
    gru    <<<256, 1024, 0, stream>>>(ch, rev_ch, w_len, fw_bhh, bw_bhh, Wf, gi, ems);
    emit   <<<BB * SS, 256, 0, stream>>>(w, w_cap, w_chs, w_mask, w_em, cap_em, ems, out);
}

// Round 5
// 554.128 us; speedup vs baseline: 1.1038x; 1.1038x over previous
//
#include <hip/hip_runtime.h>

// Problem constants
#define NW    8192
#define MAXW  20
#define BB    64
#define SS    256
#define CHS   128
#define CHE   64
#define HH    256
#define G3    768
#define WEM   300
#define CAPEM 16

typedef _Float16 half8  __attribute__((ext_vector_type(8)));
typedef _Float16 half4v __attribute__((ext_vector_type(4)));
typedef float    f32x4  __attribute__((ext_vector_type(4)));

// workspace layout (bytes)
#define WF_OFF  0                        // f16 w_hh frag-ordered, 2 dirs: 786432 B
#define GI_OFF  (2*G3*HH*2)              // f16 gi table, 2 dirs: 393216 B
#define EMS_OFF (GI_OFF + 2*CHS*G3*2)    // f32 ems, 2 dirs: 16777216 B

__device__ __forceinline__ float fast_sigmoid(float x) {
    float e = __builtin_amdgcn_exp2f(-1.442695041f * x);
    return __builtin_amdgcn_rcpf(1.0f + e);
}
__device__ __forceinline__ float fast_tanh(float x) {
    float e = __builtin_amdgcn_exp2f(2.885390082f * x);
    return 1.0f - 2.0f * __builtin_amdgcn_rcpf(1.0f + e);
}

// Fragment-ordered f16 weights: rows m = g*256 + wvv*16 + l16, k = kk*32 + q*8 + j.
// Wave's A-frag load in gru = one contiguous 1 KB segment.
__global__ void prep_w(const float* __restrict__ fw_whh, const float* __restrict__ bw_whh,
                       _Float16* __restrict__ Wf) {
    int dir = blockIdx.x / 48;
    int tile = blockIdx.x % 48;
    int g = tile >> 4, wvv = tile & 15;
    int t = threadIdx.x;                 // 512 = kk(8) * l16(16) * q(4)
    int kk = t >> 6;
    int l16 = (t >> 2) & 15;
    int q = t & 3;
    int m = g * 256 + wvv * 16 + l16;
    const float* src = (dir ? bw_whh : fw_whh) + m * HH + kk * 32 + q * 8;
    _Float16* d = Wf + (size_t)dir * G3 * HH + (((size_t)tile * 8 + kk) * 64 + l16 * 4 + q) * 8;
    #pragma unroll
    for (int j = 0; j < 8; ++j) d[j] = (_Float16)src[j];
}

// gi table (f16): gi[dir][c][j] = sum_e w_ih[j][e]*ch_em[c][e] + b_ih[j] + (j<512 ? b_hh[j] : 0)
__global__ void prep_gi(const float* __restrict__ ch_em,
                        const float* __restrict__ fw_wih, const float* __restrict__ fw_bih,
                        const float* __restrict__ fw_bhh,
                        const float* __restrict__ bw_wih, const float* __restrict__ bw_bih,
                        const float* __restrict__ bw_bhh,
                        _Float16* __restrict__ gi) {
    int bx = blockIdx.x;
    int dir = bx >> 7;
    int c = bx & 127;
    const float* wih = dir ? bw_wih : fw_wih;
    const float* bih = dir ? bw_bih : fw_bih;
    const float* bhh = dir ? bw_bhh : fw_bhh;
    const float* ce = ch_em + c * CHE;
    for (int jj = 0; jj < 3; ++jj) {
        int j = jj * 256 + threadIdx.x;
        float s = bih[j] + (j < 512 ? bhh[j] : 0.0f);
        const float* wr = wih + j * CHE;
        #pragma unroll
        for (int e = 0; e < CHE; ++e) s += wr[e] * ce[e];
        gi[(size_t)dir * CHS * G3 + c * G3 + j] = (_Float16)s;
    }
}

// GRU: 256 blocks (dir*128 + word-block) x 1024 thr (16 waves), 1 block/CU.
//
// Spill analysis (round 0/1 counters): VGPR_Count=64 + ~420 MB scratch
// WRITE + ~730 MB scratch FETCH == spill traffic; real traffic is ~30 MB.
// Cause: the backend's occupancy heuristic sees only {LDS, workgroup size}.
// At 39 KB LDS it targeted 2 blocks/CU = 8 waves/EU = 64 arch VGPRs ->
// guaranteed spill of the ~90-reg live set. Fixes:
//  (a) hprev f32 carry moved to LDS (hbuf32): removes the only persistent
//      arch-VGPR array; numerics identical (f32 carry preserved). Also
//      pushes LDS to ~104 KB -> only 1 block/CU fits -> backend occupancy
//      computation lands on 4 waves/EU -> 128-reg budget, matching
//      __launch_bounds__(1024, 4).
//  (b) gi loads issued at loop top (issue-early/consume-late) so L2 latency
//      hides under the MFMA loop instead of serializing in the gate phase.
//      acc[3][4] (48 regs) lives in AGPRs; gfx950 VALU reads AGPRs directly,
//      so peak arch demand ~60-90 <= 128 -> no spill.
__global__ __launch_bounds__(1024, 4)
void gru(const int* __restrict__ ch, const int* __restrict__ rev_ch,
         const int* __restrict__ wlen,
         const float* __restrict__ fw_bhh, const float* __restrict__ bw_bhh,
         const _Float16* __restrict__ Wf, const _Float16* __restrict__ gi,
         float* __restrict__ ems) {
    int dir = blockIdx.x >> 7;
    int wblk = blockIdx.x & 127;
    int w0 = wblk * 64;
    const int* chp = dir ? rev_ch : ch;
    const _Float16* W = Wf + (size_t)dir * G3 * HH;
    const _Float16* gt = gi + (size_t)dir * CHS * G3;
    const float* bh = dir ? bw_bhh : fw_bhh;
    float* emsd = ems + (size_t)dir * NW * HH;

    int tid = threadIdx.x;
    int wv = tid >> 6;          // 0..15 -> h cols [wv*16, wv*16+16)
    int lane = tid & 63;
    int q = lane >> 4;          // 0..3
    int l16 = lane & 15;

    __shared__ __align__(16) _Float16 hbuf[64][264];     // h (f16) for MFMA B-frags
    __shared__ __align__(16) float    hbuf32[64][264];   // h (f32) recurrence carry
    __shared__ int clds[64][MAXW];                       // chars, staged once
    __shared__ int wls[64];                              // lengths

    // one-time staging
    for (int i = tid; i < 64 * 264; i += 1024) {
        (&hbuf[0][0])[i] = (_Float16)0.0f;
        (&hbuf32[0][0])[i] = 0.0f;
    }
    if (tid < 64) wls[tid] = wlen[w0 + tid];
    for (int i = tid; i < 64 * MAXW; i += 1024) {
        int w = i / MAXW, t = i - w * MAXW;
        clds[w][t] = chp[(w0 + w) * MAXW + t];
    }
    f32x4 bhhn = *(const f32x4*)(bh + 512 + wv * 16 + q * 4);
    const f32x4 fz = {0.0f, 0.0f, 0.0f, 0.0f};
    __syncthreads();

    #pragma unroll 1
    for (int t = 0; t < MAXW; ++t) {
        // (a) gi prefetch for this step: issue the 12 L2 loads BEFORE the
        // MFMA loop; consumed after barrier (c). Statically indexed arrays.
        half4v g0p[4], g1p[4], g2p[4];
        #pragma unroll
        for (int ct = 0; ct < 4; ++ct) {
            int c = clds[ct * 16 + l16][t];
            const _Float16* gr = gt + (size_t)c * G3 + wv * 16 + q * 4;
            g0p[ct] = *(const half4v*)(gr);
            g1p[ct] = *(const half4v*)(gr + 256);
            g2p[ct] = *(const half4v*)(gr + 512);
        }

        // (b) MFMA: acc = W_hh x h^T, K = 256 in 8 k-tiles of 32
        f32x4 acc[3][4];
        #pragma unroll
        for (int g = 0; g < 3; ++g)
            #pragma unroll
            for (int ct = 0; ct < 4; ++ct) acc[g][ct] = fz;

        #pragma unroll
        for (int kk = 0; kk < 8; ++kk) {
            half8 af0 = *(const half8*)(W + (((size_t)(0 * 16 + wv) * 8 + kk) * 64 + l16 * 4 + q) * 8);
            half8 af1 = *(const half8*)(W + (((size_t)(1 * 16 + wv) * 8 + kk) * 64 + l16 * 4 + q) * 8);
            half8 af2 = *(const half8*)(W + (((size_t)(2 * 16 + wv) * 8 + kk) * 64 + l16 * 4 + q) * 8);
            #pragma unroll
            for (int ct = 0; ct < 4; ++ct) {
                half8 bf = *(const half8*)(&hbuf[ct * 16 + l16][kk * 32 + q * 8]);
                acc[0][ct] = __builtin_amdgcn_mfma_f32_16x16x32_f16(af0, bf, acc[0][ct], 0, 0, 0);
                acc[1][ct] = __builtin_amdgcn_mfma_f32_16x16x32_f16(af1, bf, acc[1][ct], 0, 0, 0);
                acc[2][ct] = __builtin_amdgcn_mfma_f32_16x16x32_f16(af2, bf, acc[2][ct], 0, 0, 0);
            }
        }

        __syncthreads();   // (c) all hbuf(t-1) reads done

        // (d) elementwise gates + h update. f32 carry read/written in LDS
        // (each (word,col) slot touched by exactly one thread -- no races).
        #pragma unroll
        for (int ct = 0; ct < 4; ++ct) {
            int word = ct * 16 + l16;
            f32x4 hv = *(const f32x4*)(&hbuf32[word][wv * 16 + q * 4]);
            f32x4 out4;
            half4v hh4;
            #pragma unroll
            for (int e = 0; e < 4; ++e) {
                float r  = fast_sigmoid(acc[0][ct][e] + (float)g0p[ct][e]);
                float z  = fast_sigmoid(acc[1][ct][e] + (float)g1p[ct][e]);
                float n  = fast_tanh((float)g2p[ct][e] + r * (acc[2][ct][e] + bhhn[e]));
                float hnew = n + z * (hv[e] - n);
                out4[e] = hnew;
                hh4[e] = (_Float16)hnew;
            }
            *(half4v*)(&hbuf[word][wv * 16 + q * 4]) = hh4;
            *(f32x4*)(&hbuf32[word][wv * 16 + q * 4]) = out4;
        }
        __syncthreads();   // (e) h(t) complete in hbuf

        // (f) coalesced ems writeback for words finishing at this step
        {
            int w = tid >> 4, t16 = tid & 15;
            if (wls[w] == t + 1) {
                const _Float16* src = &hbuf[w][t16 * 16];
                half8 a = *(const half8*)(src);
                half8 b = *(const half8*)(src + 8);
                f32x4 o0, o1, o2, o3;
                #pragma unroll
                for (int e = 0; e < 4; ++e) {
                    o0[e] = (float)a[e];     o1[e] = (float)a[4 + e];
                    o2[e] = (float)b[e];     o3[e] = (float)b[4 + e];
                }
                f32x4* dst = (f32x4*)(emsd + (size_t)(w0 + w) * HH + t16 * 16);
                dst[0] = o0; dst[1] = o1; dst[2] = o2; dst[3] = o3;
            }
        }
        // no barrier needed: (f) reads complete before any thread passes next (c)
    }
}

// Gather/concat: one block per (b,s) position; 207 f32x4 chunks of 828 f32.
// chunk map: [0,64) pre*m | [64,139) wem | [139,203) suf*m | [203,207) cap
__global__ void emit(const int* __restrict__ w, const int* __restrict__ wcap,
                     const int* __restrict__ wchs, const float* __restrict__ wmask,
                     const float* __restrict__ w_em, const float* __restrict__ cap_em,
                     const float* __restrict__ ems, float* __restrict__ out) {
    int pos = blockIdx.x;
    int c = threadIdx.x;
    if (c >= 207) return;
    int wi = w[pos], cap = wcap[pos], wch = wchs[pos];
    float m = wmask[pos];
    const f32x4* suf = (const f32x4*)(ems + (size_t)wch * HH);                   // fw = suffix
    const f32x4* pre = (const f32x4*)(ems + (size_t)NW * HH + (size_t)wch * HH); // bw = prefix
    const f32x4* wem = (const f32x4*)(w_em + (size_t)wi * WEM);
    const f32x4* cp4 = (const f32x4*)(cap_em + cap * CAPEM);
    f32x4 v;
    if (c < 64)       v = pre[c] * m;
    else if (c < 139) v = wem[c - 64];
    else if (c < 203) v = suf[c - 139] * m;
    else              v = cp4[c - 203];
    ((f32x4*)out)[(size_t)pos * 207 + c] = v;
}

extern "C" void kernel_launch(void* const* d_in, const int* in_sizes, int n_in,
                              void* d_out, int out_size, void* d_ws, size_t ws_size,
                              hipStream_t stream) {
    const int*   ch      = (const int*)d_in[0];
    const int*   rev_ch  = (const int*)d_in[1];
    const int*   w_len   = (const int*)d_in[2];
    const int*   w       = (const int*)d_in[3];
    const int*   w_cap   = (const int*)d_in[4];
    const int*   w_chs   = (const int*)d_in[5];
    const float* w_mask  = (const float*)d_in[6];
    const float* ch_em   = (const float*)d_in[7];
    const float* w_em    = (const float*)d_in[8];
    const float* cap_em  = (const float*)d_in[9];
    const float* fw_wih  = (const float*)d_in[10];
    const float* fw_whh  = (const float*)d_in[11];
    const float* fw_bih  = (const float*)d_in[12];
    const float* fw_bhh  = (const float*)d_in[13];
    const float* bw_wih  = (const float*)d_in[14];
    const float* bw_whh  = (const float*)d_in[15];
    const float* bw_bih  = (const float*)d_in[16];
    const float* bw_bhh  = (const float*)d_in[17];

    char* ws = (char*)d_ws;
    _Float16* Wf = (_Float16*)(ws + WF_OFF);
    _Float16* gi = (_Float16*)(ws + GI_OFF);
    float* ems   = (float*)(ws + EMS_OFF);
    float* out   = (float*)d_out;

    prep_w <<<96, 512, 0, stream>>>(fw_whh, bw_whh, Wf);
    prep_gi<<<256, 256, 0, stream>>>(ch_em, fw_wih, fw_bih, fw_bhh,
                                     bw_wih, bw_bih, bw_bhh, gi);
    gru    <<<256, 1024, 0, stream>>>(ch, rev_ch, w_len, fw_bhh, bw_bhh, Wf, gi, ems);
    emit   <<<BB * SS, 256, 0, stream>>>(w, w_cap, w_chs, w_mask, w_em, cap_em, ems, out);
}

// Round 6
// 511.710 us; speedup vs baseline: 1.1953x; 1.0829x over previous
//
#include <hip/hip_runtime.h>

// Problem constants
#define NW    8192
#define MAXW  20
#define BB    64
#define SS    256
#define CHS   128
#define CHE   64
#define HH    256
#define G3    768
#define WEM   300
#define CAPEM 16

typedef _Float16 half8  __attribute__((ext_vector_type(8)));
typedef _Float16 half4v __attribute__((ext_vector_type(4)));
typedef float    f32x4  __attribute__((ext_vector_type(4)));

// workspace layout (bytes)
#define WF_OFF  0                        // f16 w_hh wave-contig frag-ordered, 2 dirs: 786432 B
#define GI_OFF  (2*G3*HH*2)              // f16 gi table, 2 dirs: 393216 B
#define EMS_OFF (GI_OFF + 2*CHS*G3*2)    // f32 ems, 2 dirs: 16777216 B

__device__ __forceinline__ float fast_sigmoid(float x) {
    float e = __builtin_amdgcn_exp2f(-1.442695041f * x);
    return __builtin_amdgcn_rcpf(1.0f + e);
}
__device__ __forceinline__ float fast_tanh(float x) {
    float e = __builtin_amdgcn_exp2f(2.885390082f * x);
    return 1.0f - 2.0f * __builtin_amdgcn_rcpf(1.0f + e);
}

// Wave-contiguous fragment layout:
//   Wf[dir][wv][g][kk][lane] with lane = l16*4+q, 8 halfs (16 B) per lane.
//   halfs: dir*196608 + wv*12288 + g*4096 + kk*512 + lane*8
// In gru, a wave's ENTIRE per-step W working set is one contiguous 24 KB
// block: all 24 af loads = one per-thread base + small compile-time offsets.
// (Round-5 layout had g-stride 128 KB / kk-stride 1 KB -> 24 hoisted 64-bit
// address pairs ~ 48 dwords/thread, spilled by LICM and reloaded every
// t-step: the 10:1 FETCH:WRITE excess, 610 MB of scratch reloads.)
__global__ void prep_w(const float* __restrict__ fw_whh, const float* __restrict__ bw_whh,
                       _Float16* __restrict__ Wf) {
    int dir = blockIdx.x / 48;
    int tile = blockIdx.x % 48;
    int g = tile >> 4, wvv = tile & 15;
    int t = threadIdx.x;                 // 512 = kk(8) * l16(16) * q(4)
    int kk = t >> 6;
    int l16 = (t >> 2) & 15;
    int q = t & 3;
    int m = g * 256 + wvv * 16 + l16;    // row of w_hh
    const float* src = (dir ? bw_whh : fw_whh) + m * HH + kk * 32 + q * 8;
    _Float16* d = Wf + (size_t)dir * G3 * HH
                + (size_t)wvv * 12288 + g * 4096 + kk * 512 + (l16 * 4 + q) * 8;
    #pragma unroll
    for (int j = 0; j < 8; ++j) d[j] = (_Float16)src[j];
}

// gi table (f16): gi[dir][c][j] = sum_e w_ih[j][e]*ch_em[c][e] + b_ih[j] + (j<512 ? b_hh[j] : 0)
__global__ void prep_gi(const float* __restrict__ ch_em,
                        const float* __restrict__ fw_wih, const float* __restrict__ fw_bih,
                        const float* __restrict__ fw_bhh,
                        const float* __restrict__ bw_wih, const float* __restrict__ bw_bih,
                        const float* __restrict__ bw_bhh,
                        _Float16* __restrict__ gi) {
    int bx = blockIdx.x;
    int dir = bx >> 7;
    int c = bx & 127;
    const float* wih = dir ? bw_wih : fw_wih;
    const float* bih = dir ? bw_bih : fw_bih;
    const float* bhh = dir ? bw_bhh : fw_bhh;
    const float* ce = ch_em + c * CHE;
    for (int jj = 0; jj < 3; ++jj) {
        int j = jj * 256 + threadIdx.x;
        float s = bih[j] + (j < 512 ? bhh[j] : 0.0f);
        const float* wr = wih + j * CHE;
        #pragma unroll
        for (int e = 0; e < CHE; ++e) s += wr[e] * ce[e];
        gi[(size_t)dir * CHS * G3 + c * G3 + j] = (_Float16)s;
    }
}

// GRU: 256 blocks (dir*128 + word-block) x 1024 thr (16 waves), 1 block/CU.
//
// Register-pressure ledger (the whole game on this kernel):
//  - budget: 107 KB LDS -> 1 block/CU -> 4 waves/EU -> 128 total regs;
//    compiler splits 64 arch + 64 AGPR (acc[3][4]=48 f32 in AGPRs).
//  - arch demand must stay < 64 or LICM-hoisted loop-invariants spill and
//    get RELOADED EVERY t-STEP (round-5: 58 dwords/thread of W addresses
//    -> 61 MB spill write + 610 MB reload fetch, L2 thrashed).
//  - fixes: (1) wave-contig W layout -> 24 af loads share ONE base
//    (+ <=32 KB compile-time offsets -> ~3-6 hoisted base pairs);
//    (2) NO gi prefetch across the MFMA loop (gate-phase loads cost one
//    ~200cy L2 latency per step ~ 1.7 us total, vs 24 held regs);
//    (3) f32 carry stays in LDS (hbuf32), not 16 persistent regs.
__global__ __launch_bounds__(1024, 4)
void gru(const int* __restrict__ ch, const int* __restrict__ rev_ch,
         const int* __restrict__ wlen,
         const float* __restrict__ fw_bhh, const float* __restrict__ bw_bhh,
         const _Float16* __restrict__ Wf, const _Float16* __restrict__ gi,
         float* __restrict__ ems) {
    int dir = blockIdx.x >> 7;
    int wblk = blockIdx.x & 127;
    int w0 = wblk * 64;
    const int* chp = dir ? rev_ch : ch;
    const _Float16* W = Wf + (size_t)dir * G3 * HH;
    const _Float16* gt = gi + (size_t)dir * CHS * G3;
    const float* bh = dir ? bw_bhh : fw_bhh;
    float* emsd = ems + (size_t)dir * NW * HH;

    int tid = threadIdx.x;
    int wv = tid >> 6;          // 0..15 -> h cols [wv*16, wv*16+16)
    int lane = tid & 63;
    int q = lane >> 4;          // 0..3
    int l16 = lane & 15;

    // This wave's contiguous 24 KB W block; all af loads hang off this base.
    const _Float16* Wme = W + (size_t)wv * 12288 + (l16 * 4 + q) * 8;

    __shared__ __align__(16) _Float16 hbuf[64][264];     // h (f16) for MFMA B-frags
    __shared__ __align__(16) float    hbuf32[64][264];   // h (f32) recurrence carry
    __shared__ int clds[64][MAXW];                       // chars, staged once
    __shared__ int wls[64];                              // lengths

    // one-time staging
    for (int i = tid; i < 64 * 264; i += 1024) {
        (&hbuf[0][0])[i] = (_Float16)0.0f;
        (&hbuf32[0][0])[i] = 0.0f;
    }
    if (tid < 64) wls[tid] = wlen[w0 + tid];
    for (int i = tid; i < 64 * MAXW; i += 1024) {
        int w = i / MAXW, t = i - w * MAXW;
        clds[w][t] = chp[(w0 + w) * MAXW + t];
    }
    f32x4 bhhn = *(const f32x4*)(bh + 512 + wv * 16 + q * 4);
    const f32x4 fz = {0.0f, 0.0f, 0.0f, 0.0f};
    __syncthreads();

    #pragma unroll 1
    for (int t = 0; t < MAXW; ++t) {
        // (b) MFMA: acc = W_hh x h^T, K = 256 in 8 k-tiles of 32
        f32x4 acc[3][4];
        #pragma unroll
        for (int g = 0; g < 3; ++g)
            #pragma unroll
            for (int ct = 0; ct < 4; ++ct) acc[g][ct] = fz;

        #pragma unroll
        for (int kk = 0; kk < 8; ++kk) {
            half8 af0 = *(const half8*)(Wme + kk * 512);          //  g=0: bytes kk*1024
            half8 af1 = *(const half8*)(Wme + 4096 + kk * 512);   //  g=1: 8 KB + kk*1024
            half8 af2 = *(const half8*)(Wme + 8192 + kk * 512);   //  g=2: 16 KB + kk*1024
            #pragma unroll
            for (int ct = 0; ct < 4; ++ct) {
                half8 bf = *(const half8*)(&hbuf[ct * 16 + l16][kk * 32 + q * 8]);
                acc[0][ct] = __builtin_amdgcn_mfma_f32_16x16x32_f16(af0, bf, acc[0][ct], 0, 0, 0);
                acc[1][ct] = __builtin_amdgcn_mfma_f32_16x16x32_f16(af1, bf, acc[1][ct], 0, 0, 0);
                acc[2][ct] = __builtin_amdgcn_mfma_f32_16x16x32_f16(af2, bf, acc[2][ct], 0, 0, 0);
            }
        }

        __syncthreads();   // (c) all hbuf(t-1) reads done

        // (d) elementwise gates + h update. gi read from L2 here (addresses
        // are data-dependent -> not hoistable -> no invariant pressure);
        // f32 carry read/written in LDS (one thread per slot, no races).
        #pragma unroll
        for (int ct = 0; ct < 4; ++ct) {
            int word = ct * 16 + l16;
            int c = clds[word][t];
            const _Float16* gr = gt + (size_t)c * G3 + wv * 16 + q * 4;
            half4v g0 = *(const half4v*)(gr);
            half4v g1 = *(const half4v*)(gr + 256);
            half4v g2 = *(const half4v*)(gr + 512);
            f32x4 hv = *(const f32x4*)(&hbuf32[word][wv * 16 + q * 4]);
            f32x4 out4;
            half4v hh4;
            #pragma unroll
            for (int e = 0; e < 4; ++e) {
                float r  = fast_sigmoid(acc[0][ct][e] + (float)g0[e]);
                float z  = fast_sigmoid(acc[1][ct][e] + (float)g1[e]);
                float n  = fast_tanh((float)g2[e] + r * (acc[2][ct][e] + bhhn[e]));
                float hnew = n + z * (hv[e] - n);
                out4[e] = hnew;
                hh4[e] = (_Float16)hnew;
            }
            *(half4v*)(&hbuf[word][wv * 16 + q * 4]) = hh4;
            *(f32x4*)(&hbuf32[word][wv * 16 + q * 4]) = out4;
        }
        __syncthreads();   // (e) h(t) complete in hbuf

        // (f) coalesced ems writeback for words finishing at this step
        {
            int w = tid >> 4, t16 = tid & 15;
            if (wls[w] == t + 1) {
                const _Float16* src = &hbuf[w][t16 * 16];
                half8 a = *(const half8*)(src);
                half8 b = *(const half8*)(src + 8);
                f32x4 o0, o1, o2, o3;
                #pragma unroll
                for (int e = 0; e < 4; ++e) {
                    o0[e] = (float)a[e];     o1[e] = (float)a[4 + e];
                    o2[e] = (float)b[e];     o3[e] = (float)b[4 + e];
                }
                f32x4* dst = (f32x4*)(emsd + (size_t)(w0 + w) * HH + t16 * 16);
                dst[0] = o0; dst[1] = o1; dst[2] = o2; dst[3] = o3;
            }
        }
        // no barrier needed: (f) reads complete before any thread passes next (c)
    }
}

// Gather/concat: one block per (b,s) position; 207 f32x4 chunks of 828 f32.
// chunk map: [0,64) pre*m | [64,139) wem | [139,203) suf*m | [203,207) cap
__global__ void emit(const int* __restrict__ w, const int* __restrict__ wcap,
                     const int* __restrict__ wchs, const float* __restrict__ wmask,
                     const float* __restrict__ w_em, const float* __restrict__ cap_em,
                     const float* __restrict__ ems, float* __restrict__ out) {
    int pos = blockIdx.x;
    int c = threadIdx.x;
    if (c >= 207) return;
    int wi = w[pos], cap = wcap[pos], wch = wchs[pos];
    float m = wmask[pos];
    const f32x4* suf = (const f32x4*)(ems + (size_t)wch * HH);                   // fw = suffix
    const f32x4* pre = (const f32x4*)(ems + (size_t)NW * HH + (size_t)wch * HH); // bw = prefix
    const f32x4* wem = (const f32x4*)(w_em + (size_t)wi * WEM);
    const f32x4* cp4 = (const f32x4*)(cap_em + cap * CAPEM);
    f32x4 v;
    if (c < 64)       v = pre[c] * m;
    else if (c < 139) v = wem[c - 64];
    else if (c < 203) v = suf[c - 139] * m;
    else              v = cp4[c - 203];
    ((f32x4*)out)[(size_t)pos * 207 + c] = v;
}

extern "C" void kernel_launch(void* const* d_in, const int* in_sizes, int n_in,
                              void* d_out, int out_size, void* d_ws, size_t ws_size,
                              hipStream_t stream) {
    const int*   ch      = (const int*)d_in[0];
    const int*   rev_ch  = (const int*)d_in[1];
    const int*   w_len   = (const int*)d_in[2];
    const int*   w       = (const int*)d_in[3];
    const int*   w_cap   = (const int*)d_in[4];
    const int*   w_chs   = (const int*)d_in[5];
    const float* w_mask  = (const float*)d_in[6];
    const float* ch_em   = (const float*)d_in[7];
    const float* w_em    = (const float*)d_in[8];
    const float* cap_em  = (const float*)d_in[9];
    const float* fw_wih  = (const float*)d_in[10];
    const float* fw_whh  = (const float*)d_in[11];
    const float* fw_bih  = (const float*)d_in[12];
    const float* fw_bhh  = (const float*)d_in[13];
    const float* bw_wih  = (const float*)d_in[14];
    const float* bw_whh  = (const float*)d_in[15];
    const float* bw_bih  = (const float*)d_in[16];
    const float* bw_bhh  = (const float*)d_in[17];

    char* ws = (char*)d_ws;
    _Float16* Wf = (_Float16*)(ws + WF_OFF);
    _Float16* gi = (_Float16*)(ws + GI_OFF);
    float* ems   = (float*)(ws + EMS_OFF);
    float* out   = (float*)d_out;

    prep_w <<<96, 512, 0, stream>>>(fw_whh, bw_whh, Wf);
    prep_gi<<<256, 256, 0, stream>>>(ch_em, fw_wih, fw_bih, fw_bhh,
                                     bw_wih, bw_bih, bw_bhh, gi);
    gru    <<<256, 1024, 0, stream>>>(ch, rev_ch, w_len, fw_bhh, bw_bhh, Wf, gi, ems);
    emit   <<<BB * SS, 256, 0, stream>>>(w, w_cap, w_chs, w_mask, w_em, cap_em, ems, out);
}